// Round 15
// baseline (210.106 us; speedup 1.0000x reference)
//
#include <hip/hip_runtime.h>
#include <hip/hip_bf16.h>

typedef __bf16 bf16_t;
typedef bf16_t bf16x8 __attribute__((ext_vector_type(8)));
typedef float f32x4 __attribute__((ext_vector_type(4)));
typedef float f32x16 __attribute__((ext_vector_type(16)));

static __device__ __forceinline__ f32x4 mfma16(bf16x8 a, bf16x8 b, f32x4 c) {
  return __builtin_amdgcn_mfma_f32_16x16x32_bf16(a, b, c, 0, 0, 0);
}
static __device__ __forceinline__ f32x16 mfma32(bf16x8 a, bf16x8 b, f32x16 c) {
  return __builtin_amdgcn_mfma_f32_32x32x16_bf16(a, b, c, 0, 0, 0);
}

static __device__ __forceinline__ void gload_lds16(const bf16_t* g, bf16_t* l) {
  __builtin_amdgcn_global_load_lds(
      (const __attribute__((address_space(1))) void*)g,
      (__attribute__((address_space(3))) void*)l, 16, 0, 0);
}

static __device__ __forceinline__ unsigned pkbf(float a, float b) {
  union { bf16_t h[2]; unsigned u; } p;
  p.h[0] = (bf16_t)a; p.h[1] = (bf16_t)b;
  return p.u;
}
static __device__ __forceinline__ void pl32swap(unsigned& a, unsigned& b) {
  asm volatile("v_permlane32_swap_b32 %0, %1" : "+v"(a), "+v"(b));
}

// ---------------------------------------------------------------- prep kernel
// z 0-3: weight transposes W [1024][N] fp32 -> Wt [N][1024] bf16 (z0 scaled).
// z 4: x fp32 -> bf16 conversion (grid-stride over 2048 linear blocks).

__global__ __launch_bounds__(256) void prep_all(
    const float* __restrict__ x, bf16_t* __restrict__ xb,
    const float* __restrict__ Wq, const float* __restrict__ Wk,
    const float* __restrict__ Wv, const float* __restrict__ Wo,
    bf16_t* __restrict__ Wqt, bf16_t* __restrict__ Wkt,
    bf16_t* __restrict__ Wvt, bf16_t* __restrict__ Wot, float qscale) {
  __shared__ float tile[32][33];
  const int z = blockIdx.z;
  const int tid = threadIdx.y * 32 + threadIdx.x;
  if (z == 4) {   // cvt_x: 2048 blocks x 2048 floats
    const int id = blockIdx.y * gridDim.x + blockIdx.x;   // 0..2047
    size_t base = (size_t)id * 2048 + tid * 4;
    #pragma unroll
    for (int pass = 0; pass < 2; ++pass) {
      float4 v = *reinterpret_cast<const float4*>(x + base + pass * 1024);
      union { bf16_t h[4]; uint2 u; } pk;
      pk.h[0] = (bf16_t)v.x; pk.h[1] = (bf16_t)v.y;
      pk.h[2] = (bf16_t)v.z; pk.h[3] = (bf16_t)v.w;
      *reinterpret_cast<uint2*>(xb + base + pass * 1024) = pk.u;
    }
    return;
  }
  const float* W; bf16_t* Wt; int N; float scale = 1.0f;
  if (z == 0)      { W = Wq; Wt = Wqt; N = 2048; scale = qscale; }
  else if (z == 1) { W = Wk; Wt = Wkt; N = 2048; }
  else if (z == 2) { W = Wv; Wt = Wvt; N = 2048; }
  else             { W = Wo; Wt = Wot; N = 1024; if (blockIdx.x >= 32) return; }
  const int K = 1024;
  int n0 = blockIdx.x * 32, k0 = blockIdx.y * 32;
  int xx = threadIdx.x, y = threadIdx.y;  // 32 x 8
  #pragma unroll
  for (int i = 0; i < 32; i += 8)
    tile[y + i][xx] = W[(size_t)(k0 + y + i) * N + n0 + xx];
  __syncthreads();
  #pragma unroll
  for (int i = 0; i < 32; i += 8)
    Wt[(size_t)(n0 + y + i) * K + k0 + xx] = (bf16_t)(tile[xx][y + i] * scale);
}

// ---------------------------------------------------------------- GEMM (A[M][K] x Bt[N][K]^T)
// BK=64 as TWO verbatim 32-K slabs per barrier pair (R13, verified).

template <typename OutT>
static __device__ __forceinline__ void gemm_bt_body(const bf16_t* __restrict__ A,
                                                    const bf16_t* __restrict__ Bt,
                                                    OutT* __restrict__ C,
                                                    int M, int N, int K,
                                                    bool vtrans) {
  __shared__ bf16_t As[2][128 * 32];
  __shared__ bf16_t Bs[2][128 * 32];
  const int tid = threadIdx.x;
  const int w = tid >> 6, lane = tid & 63;
  const int g = lane >> 4, l15 = lane & 15;
  const int wm = w >> 1, wn = w & 1;

  // T1: XCD-contiguous block swizzle (n = gridDim.x*gridDim.y divisible by 8)
  const int nbx = gridDim.x;
  const int idx = blockIdx.y * nbx + blockIdx.x;
  const int qq = (nbx * gridDim.y) >> 3;
  const int sidx = (idx & 7) * qq + (idx >> 3);
  const int rowBase = (sidx / nbx) * 128, colBase = (sidx % nbx) * 128;

  const int c0 = 2 * w, c1 = 2 * w + 1;
  const int srow0 = 16 * c0 + (lane >> 2);
  const int srow1 = 16 * c1 + (lane >> 2);
  const int scol = (lane & 3) * 8;

  f32x4 acc[4][4] = {};

  for (int k0 = 0; k0 < K; k0 += 64) {
    __syncthreads();
    #pragma unroll
    for (int sl = 0; sl < 2; ++sl) {
      const int kk = k0 + sl * 32;
      gload_lds16(A + (size_t)(rowBase + srow0) * K + kk + scol, &As[sl][c0 * 512]);
      gload_lds16(A + (size_t)(rowBase + srow1) * K + kk + scol, &As[sl][c1 * 512]);
      gload_lds16(Bt + (size_t)(colBase + srow0) * K + kk + scol, &Bs[sl][c0 * 512]);
      gload_lds16(Bt + (size_t)(colBase + srow1) * K + kk + scol, &Bs[sl][c1 * 512]);
    }
    __syncthreads();

    #pragma unroll
    for (int sl = 0; sl < 2; ++sl) {
      bf16x8 bfr[4];
      #pragma unroll
      for (int j = 0; j < 4; ++j)
        bfr[j] = *reinterpret_cast<const bf16x8*>(&Bs[sl][(wn * 64 + j * 16 + l15) * 32 + g * 8]);
      #pragma unroll
      for (int i = 0; i < 4; ++i) {
        bf16x8 afr = *reinterpret_cast<const bf16x8*>(&As[sl][(wm * 64 + i * 16 + l15) * 32 + g * 8]);
        #pragma unroll
        for (int j = 0; j < 4; ++j)
          acc[i][j] = mfma16(afr, bfr[j], acc[i][j]);
      }
    }
  }

  if (vtrans) {
    #pragma unroll
    for (int i = 0; i < 4; ++i) {
      #pragma unroll
      for (int j = 0; j < 4; ++j) {
        int row = rowBase + wm * 64 + i * 16 + 4 * g;  // global s in [0,4096)
        int col = colBase + wn * 64 + j * 16 + l15;    // [0,2048)
        int bb = row >> 11, s = row & 2047;
        union { bf16_t h[4]; uint2 u; } pk;
        #pragma unroll
        for (int r = 0; r < 4; ++r) pk.h[r] = (bf16_t)acc[i][j][r];
        *reinterpret_cast<uint2*>(
            (bf16_t*)C + ((size_t)bb * 2048 + col) * 2048 + s) = pk.u;
      }
    }
  } else {
    #pragma unroll
    for (int i = 0; i < 4; ++i) {
      #pragma unroll
      for (int j = 0; j < 4; ++j) {
        int row = rowBase + wm * 64 + i * 16 + 4 * g;
        int col = colBase + wn * 64 + j * 16 + l15;
        #pragma unroll
        for (int r = 0; r < 4; ++r)
          C[(size_t)(row + r) * N + col] = (OutT)acc[i][j][r];
      }
    }
  }
}

__global__ __launch_bounds__(256) void gemm_qkv(const bf16_t* __restrict__ xb,
                                                const bf16_t* __restrict__ Wqt,
                                                const bf16_t* __restrict__ Wkt,
                                                const bf16_t* __restrict__ Wvt,
                                                bf16_t* __restrict__ Q,
                                                bf16_t* __restrict__ K,
                                                bf16_t* __restrict__ Vtg) {
  const bf16_t* Bt = (blockIdx.z == 0) ? Wqt : (blockIdx.z == 1) ? Wkt : Wvt;
  bf16_t* C = (blockIdx.z == 0) ? Q : (blockIdx.z == 1) ? K : Vtg;
  gemm_bt_body<bf16_t>(xb, Bt, C, 4096, 2048, 1024, blockIdx.z == 2);
}

__global__ __launch_bounds__(256) void gemm_out(const bf16_t* __restrict__ Ob,
                                                const bf16_t* __restrict__ Wot,
                                                float* __restrict__ out) {
  gemm_bt_body<float>(Ob, Wot, out, 4096, 1024, 1024, false);
}

// ---------------------------------------------------------------- attention
// R14 kernel with K READ DIRECTLY FROM GLOBAL (no K staging, no K LDS reads):
// the QK^T A-fragment kf is content-identical to the verified LDS read --
// kf[s] = Kg[(rowB + j0 + keyh*64 + kb*32 + l31)*2048 + comp*1024 + h*64 +
// s*16 + hi*8] (the qf pattern with row = key). This halves ds_read traffic
// (32 -> 16 b128/wave-iter), halves staged bytes (drain shorter), and lets
// the compiler issue K loads without any barrier dependency (L1-served:
// 4 rowg-waves share lines; 4 s-chunks complete each 64B line).
// V path byte-identical to R14 (waves 4-7 stage, swizzled 256B rows, LDS
// regions unchanged; K regions left as dead space -- zero address edits).
// Everything else verbatim R14: KVBLK=256 double-tile, 9 uniform iters,
// ones-B MFMA rowsum, stride-33 finalize, in-kernel lambda, setprio.

__global__ __launch_bounds__(512, 1)
void attn_kernel(const bf16_t* __restrict__ Qg, const bf16_t* __restrict__ Kg,
                 const bf16_t* __restrict__ Vtg, bf16_t* __restrict__ Og,
                 const float* __restrict__ lq1, const float* __restrict__ lk1,
                 const float* __restrict__ lq2, const float* __restrict__ lk2) {
  __shared__ __align__(16) char ldsbuf[131072];

  const int tid = threadIdx.x;
  const int w = tid >> 6, lane = tid & 63;
  const int l31 = lane & 31, hi = lane >> 5;
  const int sw7 = l31 & 7;
  const int rowg = w & 3, keyh = w >> 2;
  const int bx = blockIdx.x;
  const int p = bx >> 5;            // pair 0..7 -> tiles {p, 15-p}
  const int bh = bx & 31;
  const int b = bh >> 4, h = bh & 15;
  const int rowB = b * 2048;
  const int nd1 = (p >> 1) + 1;     // double-iters for tile p (9-nd1 for 15-p)

  // ---- lambda, computed per-wave
  float lam;
  {
    float a = lq1[lane] * lk1[lane];
    float c = lq2[lane] * lk2[lane];
    #pragma unroll
    for (int msk = 32; msk; msk >>= 1) {
      a += __shfl_xor(a, msk);
      c += __shfl_xor(c, msk);
    }
    lam = __expf(a) - __expf(c) + 0.8f;
  }

  const bf16_t one = (bf16_t)1.0f;
  const bf16x8 ones = {one, one, one, one, one, one, one, one};

  // ---- staging constants (V only; verbatim R3/R4/R7 lineage)
  const int lk4 = lane >> 4;               // V: row-within-4
  const int wv = (w - 4) & 3;
  const size_t vOff = ((size_t)b * 2048 + (wv >> 1) * 1024 + h * 64 +
                       ((wv & 1) << 5) + lk4) * 2048;               // w>=4

  auto stage = [&](char* bufb, int j0) {
    if (w >= 4) {
      const bf16_t* src = Vtg + vOff + j0;
      char* dst = bufb + 32768 + wv * 8192;
      #pragma unroll
      for (int t = 0; t < 8; ++t) {
        int sc16 = (lane & 15) ^ (((t & 1) << 2) + lk4);
        gload_lds16(src + (size_t)t * (4 * 2048) + sc16 * 8,
                    (bf16_t*)(dst + t * 1024));
      }
    }
  };

  f32x16 o[2][2];
  f32x16 lsum[2];
  bf16x8 qf[2][4];

  // ---- phase-end: combine key-half partials via freed LDS buffer
  // (stride 33 floats, conflict-free); normalize, store.
  auto finalize = [&](int q0, char* scratch) {
    float* sf = (float*)scratch;
    #pragma unroll
    for (int rd = 0; rd < 4; ++rd) {
      const int comp = rd >> 1, db = rd & 1;
      __syncthreads();
      if (w >= 4) {
        float* bp = sf + (size_t)((w - 4) * 64 + lane) * 33;
        #pragma unroll
        for (int e = 0; e < 16; ++e) bp[e] = o[comp][db][e];
        if (db == 0) {
          #pragma unroll
          for (int e = 0; e < 16; ++e) bp[16 + e] = lsum[comp][e];
        }
      }
      __syncthreads();
      if (w < 4) {
        const float* bp = sf + (size_t)(w * 64 + lane) * 33;
        #pragma unroll
        for (int e = 0; e < 16; ++e) o[comp][db][e] += bp[e];
        if (db == 0) {
          #pragma unroll
          for (int e = 0; e < 16; ++e) lsum[comp][e] += bp[16 + e];
        }
      }
    }
    __syncthreads();  // scratch reads done
    if (w < 4) {
      #pragma unroll
      for (int e = 0; e < 16; ++e) {
        int ql = (e & 3) + 8 * (e >> 2) + 4 * hi;
        float i1 = 1.f / lsum[0][e];
        float i2 = lam / lsum[1][e];
        int row = rowB + q0 + w * 32 + ql;
        size_t rb = (size_t)row * 1024 + h * 64 + l31;
        Og[rb]      = (bf16_t)((o[0][0][e] * i1 - o[1][0][e] * i2) * 0.2f);
        Og[rb + 32] = (bf16_t)((o[0][1][e] * i1 - o[1][1][e] * i2) * 0.2f);
      }
    }
  };

  #pragma unroll 1
  for (int i = 0; i < 9; ++i) {
    const int q0 = (i < nd1 ? p : 15 - p) << 7;
    const int jj0 = (i < nd1 ? i : i - nd1) << 8;   // 256-key double-tile base

    __syncthreads();               // everyone done with buffer (compute/finalize)
    stage(ldsbuf, jj0);            // sub-tile A: V keys [jj0, jj0+128)
    stage(ldsbuf + 65536, jj0 + 128);  // sub-tile B: V keys [jj0+128, jj0+256)

    if (i == 0 || i == nd1) {      // phase start under staging latency
      #pragma unroll
      for (int comp = 0; comp < 2; ++comp)
        #pragma unroll
        for (int s = 0; s < 4; ++s)
          qf[comp][s] = *reinterpret_cast<const bf16x8*>(
              Qg + (size_t)(rowB + q0 + rowg * 32 + l31) * 2048 + comp * 1024 +
              h * 64 + s * 16 + hi * 8);
      #pragma unroll
      for (int comp = 0; comp < 2; ++comp) {
        o[comp][0] = (f32x16)0.f;
        o[comp][1] = (f32x16)0.f;
        lsum[comp] = (f32x16)0.f;
      }
    }

    __syncthreads();               // staged V visible (drains vmcnt)

    const int rowbase = q0 + rowg * 32;
    const int qg = rowbase + l31;

    #pragma unroll 1
    for (int st = 0; st < 2; ++st) {
      const int j0 = jj0 + st * 128;
      const char* bufb = (const char*)ldsbuf + st * 65536;
      const bool active = (j0 + keyh * 64) <= (rowbase + 31);
      if (active) {
        const bool maskt = (j0 + keyh * 64 + 63) > rowbase;
        #pragma unroll
        for (int comp = 0; comp < 2; ++comp) {
          const char* Vb = bufb + 32768 + comp * 16384;
          // ---- per 32-key half: S' = K Q^T (K from GLOBAL) -> P -> pa -> PV
          #pragma unroll
          for (int kb = 0; kb < 2; ++kb) {
            // K fragment rows: key = j0 + keyh*64 + kb*32 + l31 (qf pattern)
            const bf16_t* Kgrow =
                Kg + (size_t)(rowB + j0 + keyh * 64 + kb * 32 + l31) * 2048 +
                comp * 1024 + h * 64;
            f32x16 sA = {};
            __builtin_amdgcn_s_setprio(1);
            #pragma unroll
            for (int s = 0; s < 4; ++s) {
              bf16x8 kf = *reinterpret_cast<const bf16x8*>(
                  Kgrow + s * 16 + hi * 8);
              sA = mfma32(kf, qf[comp][s], sA);
            }
            __builtin_amdgcn_s_setprio(0);
            float pv[16];
            #pragma unroll
            for (int e = 0; e < 16; ++e) {
              float v = __builtin_exp2f(sA[e]);   // Q pre-scaled by 0.125*log2e
              if (maskt) {
                int krow = (e & 3) + 8 * (e >> 2) + 4 * hi;
                if (j0 + keyh * 64 + kb * 32 + krow > qg) v = 0.f;
              }
              pv[e] = v;
            }
            bf16x8 pa[2];
            #pragma unroll
            for (int sp = 0; sp < 2; ++sp) {
              unsigned u0 = pkbf(pv[8 * sp + 0], pv[8 * sp + 1]);
              unsigned u1 = pkbf(pv[8 * sp + 2], pv[8 * sp + 3]);
              unsigned v0 = pkbf(pv[8 * sp + 4], pv[8 * sp + 5]);
              unsigned v1 = pkbf(pv[8 * sp + 6], pv[8 * sp + 7]);
              pl32swap(u0, v0);
              pl32swap(u1, v1);
              union { uint4 u; bf16x8 f; } cvt;
              cvt.u = make_uint4(u0, u1, v0, v1);
              pa[sp] = cvt.f;
            }
            __builtin_amdgcn_s_setprio(1);
            #pragma unroll
            for (int sp = 0; sp < 2; ++sp) {
              int s = kb * 2 + sp;
              int sl = ((keyh * 8) | ((2 * s + hi) ^ sw7)) << 4;
              bf16x8 vf0 = *reinterpret_cast<const bf16x8*>(Vb + l31 * 256 + sl);
              bf16x8 vf1 = *reinterpret_cast<const bf16x8*>(Vb + (32 + l31) * 256 + sl);
              o[comp][0] = mfma32(pa[sp], vf0, o[comp][0]);
              o[comp][1] = mfma32(pa[sp], vf1, o[comp][1]);
              lsum[comp] = mfma32(pa[sp], ones, lsum[comp]);
            }
            __builtin_amdgcn_s_setprio(0);
          }
        }
      }
    }

    if (i == nd1 - 1 || i == 8) finalize(q0, ldsbuf);
  }
}

// ---------------------------------------------------------------- launch

extern "C" void kernel_launch(void* const* d_in, const int* in_sizes, int n_in,
                              void* d_out, int out_size, void* d_ws, size_t ws_size,
                              hipStream_t stream) {
  const float* x   = (const float*)d_in[0];
  const float* Wq  = (const float*)d_in[1];
  const float* Wk  = (const float*)d_in[2];
  const float* Wv  = (const float*)d_in[3];
  const float* Wo  = (const float*)d_in[4];
  const float* lq1 = (const float*)d_in[5];
  const float* lk1 = (const float*)d_in[6];
  const float* lq2 = (const float*)d_in[7];
  const float* lk2 = (const float*)d_in[8];
  float* out = (float*)d_out;

  char* ws = (char*)d_ws;
  size_t off = 0;
  auto alloc = [&](size_t bytes) -> char* {
    char* p = ws + off;
    off += (bytes + 255) & ~(size_t)255;
    return p;
  };
  bf16_t* xb  = (bf16_t*)alloc((size_t)4096 * 1024 * 2);
  bf16_t* Wqt = (bf16_t*)alloc((size_t)2048 * 1024 * 2);
  bf16_t* Wkt = (bf16_t*)alloc((size_t)2048 * 1024 * 2);
  bf16_t* Wvt = (bf16_t*)alloc((size_t)2048 * 1024 * 2);
  bf16_t* Wot = (bf16_t*)alloc((size_t)1024 * 1024 * 2);
  bf16_t* Qb  = (bf16_t*)alloc((size_t)4096 * 2048 * 2);
  bf16_t* Kb  = (bf16_t*)alloc((size_t)4096 * 2048 * 2);
  bf16_t* Vtg = (bf16_t*)alloc((size_t)4096 * 2048 * 2);
  bf16_t* Ob  = (bf16_t*)alloc((size_t)4096 * 1024 * 2);

  const float QSCALE = 0.125f * 1.44269504088896340736f;  // fold into Wq

  prep_all<<<dim3(64, 32, 5), dim3(32, 8), 0, stream>>>(
      x, xb, Wq, Wk, Wv, Wo, Wqt, Wkt, Wvt, Wot, QSCALE);
  gemm_qkv<<<dim3(16, 32, 3), 256, 0, stream>>>(xb, Wqt, Wkt, Wvt, Qb, Kb, Vtg);
  attn_kernel<<<256, 512, 0, stream>>>(Qb, Kb, Vtg, Ob, lq1, lk1, lq2, lk2);
  gemm_out<<<dim3(8, 32), 256, 0, stream>>>(Ob, Wot, out);
}

// Round 16
// 185.793 us; speedup vs baseline: 1.1309x; 1.1309x over previous
//
#include <hip/hip_runtime.h>
#include <hip/hip_bf16.h>

typedef __bf16 bf16_t;
typedef bf16_t bf16x8 __attribute__((ext_vector_type(8)));
typedef float f32x4 __attribute__((ext_vector_type(4)));
typedef float f32x16 __attribute__((ext_vector_type(16)));

static __device__ __forceinline__ f32x4 mfma16(bf16x8 a, bf16x8 b, f32x4 c) {
  return __builtin_amdgcn_mfma_f32_16x16x32_bf16(a, b, c, 0, 0, 0);
}
static __device__ __forceinline__ f32x16 mfma32(bf16x8 a, bf16x8 b, f32x16 c) {
  return __builtin_amdgcn_mfma_f32_32x32x16_bf16(a, b, c, 0, 0, 0);
}

static __device__ __forceinline__ void gload_lds16(const bf16_t* g, bf16_t* l) {
  __builtin_amdgcn_global_load_lds(
      (const __attribute__((address_space(1))) void*)g,
      (__attribute__((address_space(3))) void*)l, 16, 0, 0);
}

static __device__ __forceinline__ unsigned pkbf(float a, float b) {
  union { bf16_t h[2]; unsigned u; } p;
  p.h[0] = (bf16_t)a; p.h[1] = (bf16_t)b;
  return p.u;
}
static __device__ __forceinline__ void pl32swap(unsigned& a, unsigned& b) {
  asm volatile("v_permlane32_swap_b32 %0, %1" : "+v"(a), "+v"(b));
}

// ---------------------------------------------------------------- prep kernel
// z 0-3: weight transposes W [1024][N] fp32 -> Wt [N][1024] bf16 (z0 scaled).
// z 4: x fp32 -> bf16 conversion (grid-stride over 2048 linear blocks).

__global__ __launch_bounds__(256) void prep_all(
    const float* __restrict__ x, bf16_t* __restrict__ xb,
    const float* __restrict__ Wq, const float* __restrict__ Wk,
    const float* __restrict__ Wv, const float* __restrict__ Wo,
    bf16_t* __restrict__ Wqt, bf16_t* __restrict__ Wkt,
    bf16_t* __restrict__ Wvt, bf16_t* __restrict__ Wot, float qscale) {
  __shared__ float tile[32][33];
  const int z = blockIdx.z;
  const int tid = threadIdx.y * 32 + threadIdx.x;
  if (z == 4) {   // cvt_x: 2048 blocks x 2048 floats
    const int id = blockIdx.y * gridDim.x + blockIdx.x;   // 0..2047
    size_t base = (size_t)id * 2048 + tid * 4;
    #pragma unroll
    for (int pass = 0; pass < 2; ++pass) {
      float4 v = *reinterpret_cast<const float4*>(x + base + pass * 1024);
      union { bf16_t h[4]; uint2 u; } pk;
      pk.h[0] = (bf16_t)v.x; pk.h[1] = (bf16_t)v.y;
      pk.h[2] = (bf16_t)v.z; pk.h[3] = (bf16_t)v.w;
      *reinterpret_cast<uint2*>(xb + base + pass * 1024) = pk.u;
    }
    return;
  }
  const float* W; bf16_t* Wt; int N; float scale = 1.0f;
  if (z == 0)      { W = Wq; Wt = Wqt; N = 2048; scale = qscale; }
  else if (z == 1) { W = Wk; Wt = Wkt; N = 2048; }
  else if (z == 2) { W = Wv; Wt = Wvt; N = 2048; }
  else             { W = Wo; Wt = Wot; N = 1024; if (blockIdx.x >= 32) return; }
  const int K = 1024;
  int n0 = blockIdx.x * 32, k0 = blockIdx.y * 32;
  int xx = threadIdx.x, y = threadIdx.y;  // 32 x 8
  #pragma unroll
  for (int i = 0; i < 32; i += 8)
    tile[y + i][xx] = W[(size_t)(k0 + y + i) * N + n0 + xx];
  __syncthreads();
  #pragma unroll
  for (int i = 0; i < 32; i += 8)
    Wt[(size_t)(n0 + y + i) * K + k0 + xx] = (bf16_t)(tile[xx][y + i] * scale);
}

// ---------------------------------------------------------------- GEMM (A[M][K] x Bt[N][K]^T)
// BK=64 as TWO verbatim 32-K slabs per barrier pair (R13, verified).

template <typename OutT>
static __device__ __forceinline__ void gemm_bt_body(const bf16_t* __restrict__ A,
                                                    const bf16_t* __restrict__ Bt,
                                                    OutT* __restrict__ C,
                                                    int M, int N, int K,
                                                    bool vtrans) {
  __shared__ bf16_t As[2][128 * 32];
  __shared__ bf16_t Bs[2][128 * 32];
  const int tid = threadIdx.x;
  const int w = tid >> 6, lane = tid & 63;
  const int g = lane >> 4, l15 = lane & 15;
  const int wm = w >> 1, wn = w & 1;

  // T1: XCD-contiguous block swizzle (n = gridDim.x*gridDim.y divisible by 8)
  const int nbx = gridDim.x;
  const int idx = blockIdx.y * nbx + blockIdx.x;
  const int qq = (nbx * gridDim.y) >> 3;
  const int sidx = (idx & 7) * qq + (idx >> 3);
  const int rowBase = (sidx / nbx) * 128, colBase = (sidx % nbx) * 128;

  const int c0 = 2 * w, c1 = 2 * w + 1;
  const int srow0 = 16 * c0 + (lane >> 2);
  const int srow1 = 16 * c1 + (lane >> 2);
  const int scol = (lane & 3) * 8;

  f32x4 acc[4][4] = {};

  for (int k0 = 0; k0 < K; k0 += 64) {
    __syncthreads();
    #pragma unroll
    for (int sl = 0; sl < 2; ++sl) {
      const int kk = k0 + sl * 32;
      gload_lds16(A + (size_t)(rowBase + srow0) * K + kk + scol, &As[sl][c0 * 512]);
      gload_lds16(A + (size_t)(rowBase + srow1) * K + kk + scol, &As[sl][c1 * 512]);
      gload_lds16(Bt + (size_t)(colBase + srow0) * K + kk + scol, &Bs[sl][c0 * 512]);
      gload_lds16(Bt + (size_t)(colBase + srow1) * K + kk + scol, &Bs[sl][c1 * 512]);
    }
    __syncthreads();

    #pragma unroll
    for (int sl = 0; sl < 2; ++sl) {
      bf16x8 bfr[4];
      #pragma unroll
      for (int j = 0; j < 4; ++j)
        bfr[j] = *reinterpret_cast<const bf16x8*>(&Bs[sl][(wn * 64 + j * 16 + l15) * 32 + g * 8]);
      #pragma unroll
      for (int i = 0; i < 4; ++i) {
        bf16x8 afr = *reinterpret_cast<const bf16x8*>(&As[sl][(wm * 64 + i * 16 + l15) * 32 + g * 8]);
        #pragma unroll
        for (int j = 0; j < 4; ++j)
          acc[i][j] = mfma16(afr, bfr[j], acc[i][j]);
      }
    }
  }

  if (vtrans) {
    #pragma unroll
    for (int i = 0; i < 4; ++i) {
      #pragma unroll
      for (int j = 0; j < 4; ++j) {
        int row = rowBase + wm * 64 + i * 16 + 4 * g;  // global s in [0,4096)
        int col = colBase + wn * 64 + j * 16 + l15;    // [0,2048)
        int bb = row >> 11, s = row & 2047;
        union { bf16_t h[4]; uint2 u; } pk;
        #pragma unroll
        for (int r = 0; r < 4; ++r) pk.h[r] = (bf16_t)acc[i][j][r];
        *reinterpret_cast<uint2*>(
            (bf16_t*)C + ((size_t)bb * 2048 + col) * 2048 + s) = pk.u;
      }
    }
  } else {
    #pragma unroll
    for (int i = 0; i < 4; ++i) {
      #pragma unroll
      for (int j = 0; j < 4; ++j) {
        int row = rowBase + wm * 64 + i * 16 + 4 * g;
        int col = colBase + wn * 64 + j * 16 + l15;
        #pragma unroll
        for (int r = 0; r < 4; ++r)
          C[(size_t)(row + r) * N + col] = (OutT)acc[i][j][r];
      }
    }
  }
}

__global__ __launch_bounds__(256) void gemm_qkv(const bf16_t* __restrict__ xb,
                                                const bf16_t* __restrict__ Wqt,
                                                const bf16_t* __restrict__ Wkt,
                                                const bf16_t* __restrict__ Wvt,
                                                bf16_t* __restrict__ Q,
                                                bf16_t* __restrict__ K,
                                                bf16_t* __restrict__ Vtg) {
  const bf16_t* Bt = (blockIdx.z == 0) ? Wqt : (blockIdx.z == 1) ? Wkt : Wvt;
  bf16_t* C = (blockIdx.z == 0) ? Q : (blockIdx.z == 1) ? K : Vtg;
  gemm_bt_body<bf16_t>(xb, Bt, C, 4096, 2048, 1024, blockIdx.z == 2);
}

__global__ __launch_bounds__(256) void gemm_out(const bf16_t* __restrict__ Ob,
                                                const bf16_t* __restrict__ Wot,
                                                float* __restrict__ out) {
  gemm_bt_body<float>(Ob, Wot, out, 4096, 1024, 1024, false);
}

// ---------------------------------------------------------------- attention
// R14 state (session best, verified 96us): KVBLK=256 as TWO verbatim 128-key
// sub-tiles per barrier pair; stage() at jj0 and jj0+128 into two 64KB
// regions, ONE drain+barrier, verified compute body per sub-tile. 9 uniform
// iters (nd1=(p>>1)+1 for tile p, 9-nd1 for 15-p; one all-masked half-tile
// skipped via `active`). K staged to LDS (R15's K-from-global regressed:
// per-fragment global latency sits on the QK^T critical path with no
// cross-wave cover; LDS staging batches all latency behind one drain).
// Q pre-scaled by 0.125*log2e in Wqt; rowsum via ones-B MFMA; stride-33
// finalize (conflict-free); in-kernel lambda; T5 setprio. LDS 128KB,
// 1 block/CU.

__global__ __launch_bounds__(512, 1)
void attn_kernel(const bf16_t* __restrict__ Qg, const bf16_t* __restrict__ Kg,
                 const bf16_t* __restrict__ Vtg, bf16_t* __restrict__ Og,
                 const float* __restrict__ lq1, const float* __restrict__ lk1,
                 const float* __restrict__ lq2, const float* __restrict__ lk2) {
  __shared__ __align__(16) char ldsbuf[131072];

  const int tid = threadIdx.x;
  const int w = tid >> 6, lane = tid & 63;
  const int l31 = lane & 31, hi = lane >> 5;
  const int sw7 = l31 & 7;
  const int rowg = w & 3, keyh = w >> 2;
  const int bx = blockIdx.x;
  const int p = bx >> 5;            // pair 0..7 -> tiles {p, 15-p}
  const int bh = bx & 31;
  const int b = bh >> 4, h = bh & 15;
  const int rowB = b * 2048;
  const int nd1 = (p >> 1) + 1;     // double-iters for tile p (9-nd1 for 15-p)

  // ---- lambda, computed per-wave
  float lam;
  {
    float a = lq1[lane] * lk1[lane];
    float c = lq2[lane] * lk2[lane];
    #pragma unroll
    for (int msk = 32; msk; msk >>= 1) {
      a += __shfl_xor(a, msk);
      c += __shfl_xor(c, msk);
    }
    lam = __expf(a) - __expf(c) + 0.8f;
  }

  const bf16_t one = (bf16_t)1.0f;
  const bf16x8 ones = {one, one, one, one, one, one, one, one};

  // ---- staging constants (verbatim R3/R4/R7 lineage)
  const int lk8 = lane >> 3;               // K: row-within-8
  const int sc8 = (lane & 7) ^ lk8;        // K: pre-swizzled source chunk
  const int lk4 = lane >> 4;               // V: row-within-4
  const int wv = (w - 4) & 3;
  const size_t kOff = (size_t)(rowB + ((w & 1) << 6) + lk8) * 2048 +
                      (w >> 1) * 1024 + h * 64 + sc8 * 8;           // w<4
  const size_t vOff = ((size_t)b * 2048 + (wv >> 1) * 1024 + h * 64 +
                       ((wv & 1) << 5) + lk4) * 2048;               // w>=4

  auto stage = [&](char* bufb, int j0) {
    if (w < 4) {
      const bf16_t* src = Kg + kOff + (size_t)j0 * 2048;
      char* dst = bufb + w * 8192;
      #pragma unroll
      for (int t = 0; t < 8; ++t)
        gload_lds16(src + (size_t)t * (8 * 2048), (bf16_t*)(dst + t * 1024));
    } else {
      const bf16_t* src = Vtg + vOff + j0;
      char* dst = bufb + 32768 + wv * 8192;
      #pragma unroll
      for (int t = 0; t < 8; ++t) {
        int sc16 = (lane & 15) ^ (((t & 1) << 2) + lk4);
        gload_lds16(src + (size_t)t * (4 * 2048) + sc16 * 8,
                    (bf16_t*)(dst + t * 1024));
      }
    }
  };

  f32x16 o[2][2];
  f32x16 lsum[2];
  bf16x8 qf[2][4];

  // ---- phase-end: combine key-half partials via freed LDS buffer
  // (stride 33 floats, conflict-free); normalize, store.
  auto finalize = [&](int q0, char* scratch) {
    float* sf = (float*)scratch;
    #pragma unroll
    for (int rd = 0; rd < 4; ++rd) {
      const int comp = rd >> 1, db = rd & 1;
      __syncthreads();
      if (w >= 4) {
        float* bp = sf + (size_t)((w - 4) * 64 + lane) * 33;
        #pragma unroll
        for (int e = 0; e < 16; ++e) bp[e] = o[comp][db][e];
        if (db == 0) {
          #pragma unroll
          for (int e = 0; e < 16; ++e) bp[16 + e] = lsum[comp][e];
        }
      }
      __syncthreads();
      if (w < 4) {
        const float* bp = sf + (size_t)(w * 64 + lane) * 33;
        #pragma unroll
        for (int e = 0; e < 16; ++e) o[comp][db][e] += bp[e];
        if (db == 0) {
          #pragma unroll
          for (int e = 0; e < 16; ++e) lsum[comp][e] += bp[16 + e];
        }
      }
    }
    __syncthreads();  // scratch reads done
    if (w < 4) {
      #pragma unroll
      for (int e = 0; e < 16; ++e) {
        int ql = (e & 3) + 8 * (e >> 2) + 4 * hi;
        float i1 = 1.f / lsum[0][e];
        float i2 = lam / lsum[1][e];
        int row = rowB + q0 + w * 32 + ql;
        size_t rb = (size_t)row * 1024 + h * 64 + l31;
        Og[rb]      = (bf16_t)((o[0][0][e] * i1 - o[1][0][e] * i2) * 0.2f);
        Og[rb + 32] = (bf16_t)((o[0][1][e] * i1 - o[1][1][e] * i2) * 0.2f);
      }
    }
  };

  #pragma unroll 1
  for (int i = 0; i < 9; ++i) {
    const int q0 = (i < nd1 ? p : 15 - p) << 7;
    const int jj0 = (i < nd1 ? i : i - nd1) << 8;   // 256-key double-tile base

    __syncthreads();               // everyone done with buffer (compute/finalize)
    stage(ldsbuf, jj0);            // sub-tile A: keys [jj0, jj0+128)
    stage(ldsbuf + 65536, jj0 + 128);  // sub-tile B: keys [jj0+128, jj0+256)

    if (i == 0 || i == nd1) {      // phase start under staging latency
      #pragma unroll
      for (int comp = 0; comp < 2; ++comp)
        #pragma unroll
        for (int s = 0; s < 4; ++s)
          qf[comp][s] = *reinterpret_cast<const bf16x8*>(
              Qg + (size_t)(rowB + q0 + rowg * 32 + l31) * 2048 + comp * 1024 +
              h * 64 + s * 16 + hi * 8);
      #pragma unroll
      for (int comp = 0; comp < 2; ++comp) {
        o[comp][0] = (f32x16)0.f;
        o[comp][1] = (f32x16)0.f;
        lsum[comp] = (f32x16)0.f;
      }
    }

    __syncthreads();               // staged data visible (drains vmcnt)

    const int rowbase = q0 + rowg * 32;
    const int qg = rowbase + l31;

    #pragma unroll 1
    for (int st = 0; st < 2; ++st) {
      const int j0 = jj0 + st * 128;
      const char* bufb = (const char*)ldsbuf + st * 65536;
      const bool active = (j0 + keyh * 64) <= (rowbase + 31);
      if (active) {
        const bool maskt = (j0 + keyh * 64 + 63) > rowbase;
        #pragma unroll
        for (int comp = 0; comp < 2; ++comp) {
          const char* Kb = bufb + comp * 16384 + keyh * 64 * 128;
          const char* Vb = bufb + 32768 + comp * 16384;
          // ---- per 32-key half: S' = K Q^T -> P -> pa -> PV + lsum
          #pragma unroll
          for (int kb = 0; kb < 2; ++kb) {
            f32x16 sA = {};
            __builtin_amdgcn_s_setprio(1);
            #pragma unroll
            for (int s = 0; s < 4; ++s) {
              int xo = ((2 * s + hi) ^ sw7) << 4;
              bf16x8 kf = *reinterpret_cast<const bf16x8*>(
                  Kb + (kb * 32 + l31) * 128 + xo);
              sA = mfma32(kf, qf[comp][s], sA);
            }
            __builtin_amdgcn_s_setprio(0);
            float pv[16];
            #pragma unroll
            for (int e = 0; e < 16; ++e) {
              float v = __builtin_exp2f(sA[e]);   // Q pre-scaled by 0.125*log2e
              if (maskt) {
                int krow = (e & 3) + 8 * (e >> 2) + 4 * hi;
                if (j0 + keyh * 64 + kb * 32 + krow > qg) v = 0.f;
              }
              pv[e] = v;
            }
            bf16x8 pa[2];
            #pragma unroll
            for (int sp = 0; sp < 2; ++sp) {
              unsigned u0 = pkbf(pv[8 * sp + 0], pv[8 * sp + 1]);
              unsigned u1 = pkbf(pv[8 * sp + 2], pv[8 * sp + 3]);
              unsigned v0 = pkbf(pv[8 * sp + 4], pv[8 * sp + 5]);
              unsigned v1 = pkbf(pv[8 * sp + 6], pv[8 * sp + 7]);
              pl32swap(u0, v0);
              pl32swap(u1, v1);
              union { uint4 u; bf16x8 f; } cvt;
              cvt.u = make_uint4(u0, u1, v0, v1);
              pa[sp] = cvt.f;
            }
            __builtin_amdgcn_s_setprio(1);
            #pragma unroll
            for (int sp = 0; sp < 2; ++sp) {
              int s = kb * 2 + sp;
              int sl = ((keyh * 8) | ((2 * s + hi) ^ sw7)) << 4;
              bf16x8 vf0 = *reinterpret_cast<const bf16x8*>(Vb + l31 * 256 + sl);
              bf16x8 vf1 = *reinterpret_cast<const bf16x8*>(Vb + (32 + l31) * 256 + sl);
              o[comp][0] = mfma32(pa[sp], vf0, o[comp][0]);
              o[comp][1] = mfma32(pa[sp], vf1, o[comp][1]);
              lsum[comp] = mfma32(pa[sp], ones, lsum[comp]);
            }
            __builtin_amdgcn_s_setprio(0);
          }
        }
      }
    }

    if (i == nd1 - 1 || i == 8) finalize(q0, ldsbuf);
  }
}

// ---------------------------------------------------------------- launch

extern "C" void kernel_launch(void* const* d_in, const int* in_sizes, int n_in,
                              void* d_out, int out_size, void* d_ws, size_t ws_size,
                              hipStream_t stream) {
  const float* x   = (const float*)d_in[0];
  const float* Wq  = (const float*)d_in[1];
  const float* Wk  = (const float*)d_in[2];
  const float* Wv  = (const float*)d_in[3];
  const float* Wo  = (const float*)d_in[4];
  const float* lq1 = (const float*)d_in[5];
  const float* lk1 = (const float*)d_in[6];
  const float* lq2 = (const float*)d_in[7];
  const float* lk2 = (const float*)d_in[8];
  float* out = (float*)d_out;

  char* ws = (char*)d_ws;
  size_t off = 0;
  auto alloc = [&](size_t bytes) -> char* {
    char* p = ws + off;
    off += (bytes + 255) & ~(size_t)255;
    return p;
  };
  bf16_t* xb  = (bf16_t*)alloc((size_t)4096 * 1024 * 2);
  bf16_t* Wqt = (bf16_t*)alloc((size_t)2048 * 1024 * 2);
  bf16_t* Wkt = (bf16_t*)alloc((size_t)2048 * 1024 * 2);
  bf16_t* Wvt = (bf16_t*)alloc((size_t)2048 * 1024 * 2);
  bf16_t* Wot = (bf16_t*)alloc((size_t)1024 * 1024 * 2);
  bf16_t* Qb  = (bf16_t*)alloc((size_t)4096 * 2048 * 2);
  bf16_t* Kb  = (bf16_t*)alloc((size_t)4096 * 2048 * 2);
  bf16_t* Vtg = (bf16_t*)alloc((size_t)4096 * 2048 * 2);
  bf16_t* Ob  = (bf16_t*)alloc((size_t)4096 * 1024 * 2);

  const float QSCALE = 0.125f * 1.44269504088896340736f;  // fold into Wq

  prep_all<<<dim3(64, 32, 5), dim3(32, 8), 0, stream>>>(
      x, xb, Wq, Wk, Wv, Wo, Wqt, Wkt, Wvt, Wot, QSCALE);
  gemm_qkv<<<dim3(16, 32, 3), 256, 0, stream>>>(xb, Wqt, Wkt, Wvt, Qb, Kb, Vtg);
  attn_kernel<<<256, 512, 0, stream>>>(Qb, Kb, Vtg, Ob, lq1, lk1, lq2, lk2);
  gemm_out<<<dim3(8, 32), 256, 0, stream>>>(Ob, Wot, out);
}